// Round 2
// baseline (23924.870 us; speedup 1.0000x reference)
//
#include <hip/hip_runtime.h>

#define LSEQ 512
#define NIN 1024
#define NH 2048
#define NV 50257
#define NG 8192  /* 4*NH */

// ---------------------------------------------------------------------------
// GEMM: C[M,N] = A[M,K] @ B[N,K]^T + bias1[n] (+ bias2[n] if non-null)
// BM=BN=128, BK=32, 256 threads, 8x8 microtile per thread. fp32.
// ---------------------------------------------------------------------------
__global__ __launch_bounds__(256, 2)
void gemm_abT(const float* __restrict__ A, const float* __restrict__ B,
              const float* __restrict__ bias1, const float* __restrict__ bias2,
              float* __restrict__ C, int M, int N, int K)
{
    __shared__ float As[32][128];   // [k][m]
    __shared__ float Bs[32][128];   // [k][n]
    const int tid = threadIdx.x;
    const int m0 = blockIdx.y * 128;
    const int n0 = blockIdx.x * 128;
    const int tx = tid & 15;        // n-dir
    const int ty = tid >> 4;        // m-dir
    const int lrow = tid >> 1;      // 0..127 row to load
    const int lk0  = (tid & 1) << 4; // 0 or 16

    float acc[8][8];
#pragma unroll
    for (int i = 0; i < 8; ++i)
#pragma unroll
        for (int j = 0; j < 8; ++j) acc[i][j] = 0.f;

    const bool bvalid = (n0 + lrow) < N;

    for (int k0 = 0; k0 < K; k0 += 32) {
        float4 va[4], vb[4];
        {
            const float* pa = A + (size_t)(m0 + lrow) * K + k0 + lk0;
#pragma unroll
            for (int q = 0; q < 4; ++q) va[q] = *(const float4*)(pa + 4 * q);
        }
#pragma unroll
        for (int q = 0; q < 4; ++q) vb[q] = make_float4(0.f, 0.f, 0.f, 0.f);
        if (bvalid) {
            const float* pb = B + (size_t)(n0 + lrow) * K + k0 + lk0;
#pragma unroll
            for (int q = 0; q < 4; ++q) vb[q] = *(const float4*)(pb + 4 * q);
        }
#pragma unroll
        for (int q = 0; q < 4; ++q) {
            As[lk0 + 4 * q + 0][lrow] = va[q].x;
            As[lk0 + 4 * q + 1][lrow] = va[q].y;
            As[lk0 + 4 * q + 2][lrow] = va[q].z;
            As[lk0 + 4 * q + 3][lrow] = va[q].w;
            Bs[lk0 + 4 * q + 0][lrow] = vb[q].x;
            Bs[lk0 + 4 * q + 1][lrow] = vb[q].y;
            Bs[lk0 + 4 * q + 2][lrow] = vb[q].z;
            Bs[lk0 + 4 * q + 3][lrow] = vb[q].w;
        }
        __syncthreads();

#pragma unroll 4
        for (int kk = 0; kk < 32; ++kk) {
            const float4 a0 = *(const float4*)&As[kk][ty * 8];
            const float4 a1 = *(const float4*)&As[kk][ty * 8 + 4];
            const float4 b0 = *(const float4*)&Bs[kk][tx * 8];
            const float4 b1 = *(const float4*)&Bs[kk][tx * 8 + 4];
            const float av[8] = {a0.x, a0.y, a0.z, a0.w, a1.x, a1.y, a1.z, a1.w};
            const float bv[8] = {b0.x, b0.y, b0.z, b0.w, b1.x, b1.y, b1.z, b1.w};
#pragma unroll
            for (int i = 0; i < 8; ++i)
#pragma unroll
                for (int j = 0; j < 8; ++j)
                    acc[i][j] = fmaf(av[i], bv[j], acc[i][j]);
        }
        __syncthreads();
    }

#pragma unroll
    for (int j = 0; j < 8; ++j) {
        const int n = n0 + tx * 8 + j;
        if (n >= N) continue;
        const float bb = bias1[n] + (bias2 ? bias2[n] : 0.f);
#pragma unroll
        for (int i = 0; i < 8; ++i) {
            const int m = m0 + ty * 8 + i;
            C[(size_t)m * N + n] = acc[i][j] + bb;
        }
    }
}

// ---------------------------------------------------------------------------
// Persistent sequential LSTM. 256 WGs x 512 threads. WG k owns hidden units
// [8k, 8k+8) -> 32 gate rows. Each thread holds 128 fp32 W_hh weights in 32
// EXPLICITLY-NAMED float4 registers (no indexable array -> no scratch).
// Per step: stage h (8KB) to LDS, 128 FMA/thread, 16-lane shuffle reduce,
// gate nonlinearity on 8 threads, distributed-flag grid barrier.
// ---------------------------------------------------------------------------
__device__ __forceinline__ float sigmoidf_(float x)
{
    return 1.f / (1.f + __expf(-x));
}

// Distributed release/acquire grid barrier: WG wg publishes flag[wg*16]=sv
// (monotonic per call; flags zeroed by memset each launch). 256 threads each
// spin on one flag line (64B stride).
__device__ __forceinline__ void flag_barrier(unsigned int* flags, int wg, int tid, unsigned int sv)
{
    __syncthreads();
    if (tid == 0) {
        __threadfence();  // release: make h stores visible at agent scope
        __hip_atomic_store(&flags[wg * 16], sv, __ATOMIC_RELAXED, __HIP_MEMORY_SCOPE_AGENT);
    }
    if (tid < 256) {
        while (__hip_atomic_load(&flags[tid * 16], __ATOMIC_RELAXED, __HIP_MEMORY_SCOPE_AGENT) < sv) {
        }
        __threadfence();  // acquire: invalidate caches before reading fresh h
    }
    __syncthreads();
}

#define W_LIST(F) F(0) F(1) F(2) F(3) F(4) F(5) F(6) F(7) F(8) F(9) F(10) F(11) \
  F(12) F(13) F(14) F(15) F(16) F(17) F(18) F(19) F(20) F(21) F(22) F(23) \
  F(24) F(25) F(26) F(27) F(28) F(29) F(30) F(31)
#define DECLW(I) float4 w##I;
#define LOADW(I) w##I = wp4[I];

#define CHUNK(CH, A, B, C, D) do { \
    const float4 ha = *(const float4*)&h_s[hbase + (CH) * 16 + 0]; \
    const float4 hb = *(const float4*)&h_s[hbase + (CH) * 16 + 4]; \
    const float4 hc = *(const float4*)&h_s[hbase + (CH) * 16 + 8]; \
    const float4 hd = *(const float4*)&h_s[hbase + (CH) * 16 + 12]; \
    p0 = fmaf(A.x, ha.x, p0); p0 = fmaf(A.y, ha.y, p0); \
    p0 = fmaf(A.z, ha.z, p0); p0 = fmaf(A.w, ha.w, p0); \
    p1 = fmaf(B.x, hb.x, p1); p1 = fmaf(B.y, hb.y, p1); \
    p1 = fmaf(B.z, hb.z, p1); p1 = fmaf(B.w, hb.w, p1); \
    p2 = fmaf(C.x, hc.x, p2); p2 = fmaf(C.y, hc.y, p2); \
    p2 = fmaf(C.z, hc.z, p2); p2 = fmaf(C.w, hc.w, p2); \
    p3 = fmaf(D.x, hd.x, p3); p3 = fmaf(D.y, hd.y, p3); \
    p3 = fmaf(D.z, hd.z, p3); p3 = fmaf(D.w, hd.w, p3); \
} while (0)

// One LSTM step. GS = global step (picks h double-buffer parity), T = index
// into XP. LAST skips the trailing h-publish + barrier. STOREHD writes Hd.
#define STEP(XP, T, GS, LAST, STOREHD) do { \
    { const float4 hv = *(const float4*)(hbuf + ((GS) & 1) * NH + tid * 4); \
      *(float4*)&h_s[tid * 4 + ((tid >> 5) << 2)] = hv; } \
    float xc = 0.f; \
    if (sub == 0) xc = (XP)[(size_t)(T) * NG + grow]; \
    __syncthreads(); \
    float p0 = 0.f, p1 = 0.f, p2 = 0.f, p3 = 0.f; \
    CHUNK(0, w0, w1, w2, w3);     CHUNK(1, w4, w5, w6, w7); \
    CHUNK(2, w8, w9, w10, w11);   CHUNK(3, w12, w13, w14, w15); \
    CHUNK(4, w16, w17, w18, w19); CHUNK(5, w20, w21, w22, w23); \
    CHUNK(6, w24, w25, w26, w27); CHUNK(7, w28, w29, w30, w31); \
    float partial = (p0 + p1) + (p2 + p3); \
    partial += __shfl_xor(partial, 1); \
    partial += __shfl_xor(partial, 2); \
    partial += __shfl_xor(partial, 4); \
    partial += __shfl_xor(partial, 8); \
    if (sub == 0) gates_s[row] = partial + xc; \
    __syncthreads(); \
    if (tid < 8) { \
        const float ig = sigmoidf_(gates_s[tid]); \
        const float fg = sigmoidf_(gates_s[8 + tid]); \
        const float gg = tanhf(gates_s[16 + tid]); \
        const float og = sigmoidf_(gates_s[24 + tid]); \
        const float cn = fg * c_s[tid] + ig * gg; \
        c_s[tid] = cn; \
        const float hn = og * tanhf(cn); \
        if (STOREHD) Hd[(size_t)(T) * NH + wg * 8 + tid] = hn; \
        if (!(LAST)) hbuf[(((GS) + 1) & 1) * NH + wg * 8 + tid] = hn; \
    } \
    if (!(LAST)) { flag_barrier(flags, wg, tid, sv); ++sv; } \
} while (0)

__global__ __launch_bounds__(512, 2)
void seq_lstm(const float* __restrict__ Whh_e,
              const float* __restrict__ Whh_d,
              const float* __restrict__ Xe,   // [LSEQ][NG] = Wih_e@src + biases
              const float* __restrict__ Xd,   // [LSEQ][NG]
              float* __restrict__ hbuf,       // [2][NH] double-buffered h
              float* __restrict__ Hd,         // [LSEQ][NH] decoder h history
              unsigned int* __restrict__ flags)
{
    const int wg   = blockIdx.x;        // 0..255
    const int tid  = threadIdx.x;       // 0..511
    const int lane = tid & 63;
    const int wv   = tid >> 6;          // 0..7
    const int row  = (wv << 2) + (lane >> 4);  // local gate-row 0..31
    const int sub  = lane & 15;                // 16 threads per row
    const int gate = row >> 3;
    const int u    = row & 7;
    const int grow = gate * NH + wg * 8 + u;   // global gate row in [0,8192)
    const int hbase = sub * 132;               // swizzled LDS base

    __shared__ float h_s[2112];   // 2048 + pad 4/128-seg (kills stride conflicts)
    __shared__ float gates_s[32];
    __shared__ float c_s[8];

    W_LIST(DECLW)

    // load encoder recurrent weights into named registers
    {
        const float4* wp4 = (const float4*)(Whh_e + (size_t)grow * NH + sub * 128);
        W_LIST(LOADW)
    }

    if (tid < 8) {
        c_s[tid] = 0.f;
        hbuf[wg * 8 + tid] = 0.f;   // h0 = 0 in buffer 0
    }

    unsigned int sv = 1;
    flag_barrier(flags, wg, tid, sv); ++sv;

    // ---- encoder: steps gs = 0..511 ----
#pragma unroll 1
    for (int t = 0; t < LSEQ; ++t) {
        STEP(Xe, t, t, false, false);
    }

    // ---- switch to decoder weights (h,c carry over = "memory") ----
    {
        const float4* wp4 = (const float4*)(Whh_d + (size_t)grow * NH + sub * 128);
        W_LIST(LOADW)
    }

    // ---- decoder: steps gs = 512..1023 ----
#pragma unroll 1
    for (int t = 0; t < LSEQ; ++t) {
        STEP(Xd, t, LSEQ + t, (t == LSEQ - 1), true);
    }
}

// ---------------------------------------------------------------------------
extern "C" void kernel_launch(void* const* d_in, const int* in_sizes, int n_in,
                              void* d_out, int out_size, void* d_ws, size_t ws_size,
                              hipStream_t stream)
{
    const float* src   = (const float*)d_in[0];
    const float* tgt   = (const float*)d_in[1];
    const float* Wih_e = (const float*)d_in[2];
    const float* Whh_e = (const float*)d_in[3];
    const float* bih_e = (const float*)d_in[4];
    const float* bhh_e = (const float*)d_in[5];
    const float* Wih_d = (const float*)d_in[6];
    const float* Whh_d = (const float*)d_in[7];
    const float* bih_d = (const float*)d_in[8];
    const float* bhh_d = (const float*)d_in[9];
    const float* Wout  = (const float*)d_in[10];
    const float* bout  = (const float*)d_in[11];
    float* out = (float*)d_out;

    // workspace layout (bytes):
    //   [0, 16K)      flags[256] at 64B stride (zeroed every call)
    //   [16K, 32K)    hbuf[2][2048]
    //   [+, +4MB)     Hd[512][2048]
    //   [+, +16MB)    Xe[512][8192]
    //   [+, +16MB)    Xd[512][8192]
    char* ws = (char*)d_ws;
    unsigned int* flags = (unsigned int*)ws;
    float* hbuf = (float*)(ws + 16384);
    float* Hd   = (float*)(ws + 32768);
    float* Xe   = (float*)(ws + 32768 + (size_t)LSEQ * NH * 4);
    float* Xd   = Xe + (size_t)LSEQ * NG;

    hipMemsetAsync(ws, 0, 16384, stream);

    const dim3 blk(256);
    gemm_abT<<<dim3(NG / 128, LSEQ / 128), blk, 0, stream>>>(
        src, Wih_e, bih_e, bhh_e, Xe, LSEQ, NG, NIN);
    gemm_abT<<<dim3(NG / 128, LSEQ / 128), blk, 0, stream>>>(
        tgt, Wih_d, bih_d, bhh_d, Xd, LSEQ, NG, NIN);

    seq_lstm<<<dim3(256), dim3(512), 0, stream>>>(
        Whh_e, Whh_d, Xe, Xd, hbuf, Hd, flags);

    gemm_abT<<<dim3((NV + 127) / 128, LSEQ / 128), blk, 0, stream>>>(
        Hd, Wout, bout, nullptr, out, LSEQ, NV, NH);
}

// Round 3
// 23921.449 us; speedup vs baseline: 1.0001x; 1.0001x over previous
//
#include <hip/hip_runtime.h>

#define LSEQ 512
#define NIN 1024
#define NH 2048
#define NV 50257
#define NG 8192  /* 4*NH */

typedef float f32x4 __attribute__((ext_vector_type(4)));

// ---------------------------------------------------------------------------
// GEMM: C[M,N] = A[M,K] @ B[N,K]^T + bias1[n] (+ bias2[n] if non-null)
// BM=BN=128, BK=32, 256 threads, 8x8 microtile per thread. fp32. (unchanged)
// ---------------------------------------------------------------------------
__global__ __launch_bounds__(256, 2)
void gemm_abT(const float* __restrict__ A, const float* __restrict__ B,
              const float* __restrict__ bias1, const float* __restrict__ bias2,
              float* __restrict__ C, int M, int N, int K)
{
    __shared__ float As[32][128];   // [k][m]
    __shared__ float Bs[32][128];   // [k][n]
    const int tid = threadIdx.x;
    const int m0 = blockIdx.y * 128;
    const int n0 = blockIdx.x * 128;
    const int tx = tid & 15;        // n-dir
    const int ty = tid >> 4;        // m-dir
    const int lrow = tid >> 1;      // 0..127 row to load
    const int lk0  = (tid & 1) << 4; // 0 or 16

    float acc[8][8];
#pragma unroll
    for (int i = 0; i < 8; ++i)
#pragma unroll
        for (int j = 0; j < 8; ++j) acc[i][j] = 0.f;

    const bool bvalid = (n0 + lrow) < N;

    for (int k0 = 0; k0 < K; k0 += 32) {
        float4 va[4], vb[4];
        {
            const float* pa = A + (size_t)(m0 + lrow) * K + k0 + lk0;
#pragma unroll
            for (int q = 0; q < 4; ++q) va[q] = *(const float4*)(pa + 4 * q);
        }
#pragma unroll
        for (int q = 0; q < 4; ++q) vb[q] = make_float4(0.f, 0.f, 0.f, 0.f);
        if (bvalid) {
            const float* pb = B + (size_t)(n0 + lrow) * K + k0 + lk0;
#pragma unroll
            for (int q = 0; q < 4; ++q) vb[q] = *(const float4*)(pb + 4 * q);
        }
#pragma unroll
        for (int q = 0; q < 4; ++q) {
            As[lk0 + 4 * q + 0][lrow] = va[q].x;
            As[lk0 + 4 * q + 1][lrow] = va[q].y;
            As[lk0 + 4 * q + 2][lrow] = va[q].z;
            As[lk0 + 4 * q + 3][lrow] = va[q].w;
            Bs[lk0 + 4 * q + 0][lrow] = vb[q].x;
            Bs[lk0 + 4 * q + 1][lrow] = vb[q].y;
            Bs[lk0 + 4 * q + 2][lrow] = vb[q].z;
            Bs[lk0 + 4 * q + 3][lrow] = vb[q].w;
        }
        __syncthreads();

#pragma unroll 4
        for (int kk = 0; kk < 32; ++kk) {
            const float4 a0 = *(const float4*)&As[kk][ty * 8];
            const float4 a1 = *(const float4*)&As[kk][ty * 8 + 4];
            const float4 b0 = *(const float4*)&Bs[kk][tx * 8];
            const float4 b1 = *(const float4*)&Bs[kk][tx * 8 + 4];
            const float av[8] = {a0.x, a0.y, a0.z, a0.w, a1.x, a1.y, a1.z, a1.w};
            const float bv[8] = {b0.x, b0.y, b0.z, b0.w, b1.x, b1.y, b1.z, b1.w};
#pragma unroll
            for (int i = 0; i < 8; ++i)
#pragma unroll
                for (int j = 0; j < 8; ++j)
                    acc[i][j] = fmaf(av[i], bv[j], acc[i][j]);
        }
        __syncthreads();
    }

#pragma unroll
    for (int j = 0; j < 8; ++j) {
        const int n = n0 + tx * 8 + j;
        if (n >= N) continue;
        const float bb = bias1[n] + (bias2 ? bias2[n] : 0.f);
#pragma unroll
        for (int i = 0; i < 8; ++i) {
            const int m = m0 + ty * 8 + i;
            C[(size_t)m * N + n] = acc[i][j] + bb;
        }
    }
}

// ---------------------------------------------------------------------------
// Persistent sequential LSTM. 256 WGs x 512 threads. WG k owns hidden units
// [8k, 8k+8) -> 32 gate rows. Each thread holds 128 fp32 W_hh weights in 32
// float4 registers, PINNED via asm volatile("" : "+v") so the compiler
// cannot sink the loads back into the loop (the round-1/2 failure mode:
// VGPR=88, weights re-streamed from L3 at 21.6us/step).
// ---------------------------------------------------------------------------
__device__ __forceinline__ float sigmoidf_(float x)
{
    return 1.f / (1.f + __expf(-x));
}

// Distributed release/acquire grid barrier: WG wg publishes flag[wg*16]=sv
// (monotonic per call; flags zeroed by memset each launch). 256 threads each
// spin on one flag line (64B stride).
__device__ __forceinline__ void flag_barrier(unsigned int* flags, int wg, int tid, unsigned int sv)
{
    __syncthreads();
    if (tid == 0) {
        __threadfence();  // release: make h stores visible at agent scope
        __hip_atomic_store(&flags[wg * 16], sv, __ATOMIC_RELAXED, __HIP_MEMORY_SCOPE_AGENT);
    }
    if (tid < 256) {
        while (__hip_atomic_load(&flags[tid * 16], __ATOMIC_RELAXED, __HIP_MEMORY_SCOPE_AGENT) < sv) {
        }
        __threadfence();  // acquire: invalidate caches before reading fresh h
    }
    __syncthreads();
}

#define W_LIST(F) F(0) F(1) F(2) F(3) F(4) F(5) F(6) F(7) F(8) F(9) F(10) F(11) \
  F(12) F(13) F(14) F(15) F(16) F(17) F(18) F(19) F(20) F(21) F(22) F(23) \
  F(24) F(25) F(26) F(27) F(28) F(29) F(30) F(31)
#define DECLW(I) f32x4 w##I;
#define LOADW(I) w##I = wp4[I];
// The empty asm "writes" the quad: reloading from memory is no longer a legal
// materialization, so the value MUST stay live in VGPRs.
#define PINW(I)  asm volatile("" : "+v"(w##I));

#define CHUNK(CH, A, B, C, D) do { \
    const f32x4 ha = *(const f32x4*)&h_s[hbase + (CH) * 16 + 0]; \
    const f32x4 hb = *(const f32x4*)&h_s[hbase + (CH) * 16 + 4]; \
    const f32x4 hc = *(const f32x4*)&h_s[hbase + (CH) * 16 + 8]; \
    const f32x4 hd = *(const f32x4*)&h_s[hbase + (CH) * 16 + 12]; \
    p0 = fmaf(A.x, ha.x, p0); p0 = fmaf(A.y, ha.y, p0); \
    p0 = fmaf(A.z, ha.z, p0); p0 = fmaf(A.w, ha.w, p0); \
    p1 = fmaf(B.x, hb.x, p1); p1 = fmaf(B.y, hb.y, p1); \
    p1 = fmaf(B.z, hb.z, p1); p1 = fmaf(B.w, hb.w, p1); \
    p2 = fmaf(C.x, hc.x, p2); p2 = fmaf(C.y, hc.y, p2); \
    p2 = fmaf(C.z, hc.z, p2); p2 = fmaf(C.w, hc.w, p2); \
    p3 = fmaf(D.x, hd.x, p3); p3 = fmaf(D.y, hd.y, p3); \
    p3 = fmaf(D.z, hd.z, p3); p3 = fmaf(D.w, hd.w, p3); \
} while (0)

// One LSTM step. GS = global step (picks h double-buffer parity), T = index
// into XP. LAST skips the trailing h-publish + barrier. STOREHD writes Hd.
#define STEP(XP, T, GS, LAST, STOREHD) do { \
    { const f32x4 hv = *(const f32x4*)(hbuf + ((GS) & 1) * NH + tid * 4); \
      *(f32x4*)&h_s[tid * 4 + ((tid >> 5) << 2)] = hv; } \
    float xc = 0.f; \
    if (sub == 0) xc = (XP)[(size_t)(T) * NG + grow]; \
    __syncthreads(); \
    float p0 = 0.f, p1 = 0.f, p2 = 0.f, p3 = 0.f; \
    CHUNK(0, w0, w1, w2, w3);     CHUNK(1, w4, w5, w6, w7); \
    CHUNK(2, w8, w9, w10, w11);   CHUNK(3, w12, w13, w14, w15); \
    CHUNK(4, w16, w17, w18, w19); CHUNK(5, w20, w21, w22, w23); \
    CHUNK(6, w24, w25, w26, w27); CHUNK(7, w28, w29, w30, w31); \
    float partial = (p0 + p1) + (p2 + p3); \
    partial += __shfl_xor(partial, 1); \
    partial += __shfl_xor(partial, 2); \
    partial += __shfl_xor(partial, 4); \
    partial += __shfl_xor(partial, 8); \
    if (sub == 0) gates_s[row] = partial + xc; \
    __syncthreads(); \
    if (tid < 8) { \
        const float ig = sigmoidf_(gates_s[tid]); \
        const float fg = sigmoidf_(gates_s[8 + tid]); \
        const float gg = tanhf(gates_s[16 + tid]); \
        const float og = sigmoidf_(gates_s[24 + tid]); \
        const float cn = fg * c_s[tid] + ig * gg; \
        c_s[tid] = cn; \
        const float hn = og * tanhf(cn); \
        if (STOREHD) Hd[(size_t)(T) * NH + wg * 8 + tid] = hn; \
        if (!(LAST)) hbuf[(((GS) + 1) & 1) * NH + wg * 8 + tid] = hn; \
    } \
    if (!(LAST)) { flag_barrier(flags, wg, tid, sv); ++sv; } \
} while (0)

__global__ __launch_bounds__(512, 2)
void seq_lstm(const float* __restrict__ Whh_e,
              const float* __restrict__ Whh_d,
              const float* __restrict__ Xe,   // [LSEQ][NG] = Wih_e@src + biases
              const float* __restrict__ Xd,   // [LSEQ][NG]
              float* __restrict__ hbuf,       // [2][NH] double-buffered h
              float* __restrict__ Hd,         // [LSEQ][NH] decoder h history
              unsigned int* __restrict__ flags)
{
    const int wg   = blockIdx.x;        // 0..255
    const int tid  = threadIdx.x;       // 0..511
    const int lane = tid & 63;
    const int wv   = tid >> 6;          // 0..7
    const int row  = (wv << 2) + (lane >> 4);  // local gate-row 0..31
    const int sub  = lane & 15;                // 16 threads per row
    const int gate = row >> 3;
    const int u    = row & 7;
    const int grow = gate * NH + wg * 8 + u;   // global gate row in [0,8192)
    const int hbase = sub * 132;               // swizzled LDS base

    __shared__ float h_s[2112];   // 2048 + pad 4/128-seg (kills stride conflicts)
    __shared__ float gates_s[32];
    __shared__ float c_s[8];

    W_LIST(DECLW)

    // load encoder recurrent weights into registers and PIN them there
    {
        const f32x4* wp4 = (const f32x4*)(Whh_e + (size_t)grow * NH + sub * 128);
        W_LIST(LOADW)
        W_LIST(PINW)
    }

    if (tid < 8) {
        c_s[tid] = 0.f;
        hbuf[wg * 8 + tid] = 0.f;   // h0 = 0 in buffer 0
    }

    unsigned int sv = 1;
    flag_barrier(flags, wg, tid, sv); ++sv;

    // ---- encoder: steps gs = 0..511 ----
#pragma unroll 1
    for (int t = 0; t < LSEQ; ++t) {
        STEP(Xe, t, t, false, false);
    }

    // ---- switch to decoder weights (h,c carry over = "memory") ----
    {
        const f32x4* wp4 = (const f32x4*)(Whh_d + (size_t)grow * NH + sub * 128);
        W_LIST(LOADW)
        W_LIST(PINW)
    }

    // ---- decoder: steps gs = 512..1023 ----
#pragma unroll 1
    for (int t = 0; t < LSEQ; ++t) {
        STEP(Xd, t, LSEQ + t, (t == LSEQ - 1), true);
    }
}

// ---------------------------------------------------------------------------
extern "C" void kernel_launch(void* const* d_in, const int* in_sizes, int n_in,
                              void* d_out, int out_size, void* d_ws, size_t ws_size,
                              hipStream_t stream)
{
    const float* src   = (const float*)d_in[0];
    const float* tgt   = (const float*)d_in[1];
    const float* Wih_e = (const float*)d_in[2];
    const float* Whh_e = (const float*)d_in[3];
    const float* bih_e = (const float*)d_in[4];
    const float* bhh_e = (const float*)d_in[5];
    const float* Wih_d = (const float*)d_in[6];
    const float* Whh_d = (const float*)d_in[7];
    const float* bih_d = (const float*)d_in[8];
    const float* bhh_d = (const float*)d_in[9];
    const float* Wout  = (const float*)d_in[10];
    const float* bout  = (const float*)d_in[11];
    float* out = (float*)d_out;

    // workspace layout (bytes):
    //   [0, 16K)      flags[256] at 64B stride (zeroed every call)
    //   [16K, 32K)    hbuf[2][2048]
    //   [+, +4MB)     Hd[512][2048]
    //   [+, +16MB)    Xe[512][8192]
    //   [+, +16MB)    Xd[512][8192]
    char* ws = (char*)d_ws;
    unsigned int* flags = (unsigned int*)ws;
    float* hbuf = (float*)(ws + 16384);
    float* Hd   = (float*)(ws + 32768);
    float* Xe   = (float*)(ws + 32768 + (size_t)LSEQ * NH * 4);
    float* Xd   = Xe + (size_t)LSEQ * NG;

    hipMemsetAsync(ws, 0, 16384, stream);

    const dim3 blk(256);
    gemm_abT<<<dim3(NG / 128, LSEQ / 128), blk, 0, stream>>>(
        src, Wih_e, bih_e, bhh_e, Xe, LSEQ, NG, NIN);
    gemm_abT<<<dim3(NG / 128, LSEQ / 128), blk, 0, stream>>>(
        tgt, Wih_d, bih_d, bhh_d, Xd, LSEQ, NG, NIN);

    seq_lstm<<<dim3(256), dim3(512), 0, stream>>>(
        Whh_e, Whh_d, Xe, Xd, hbuf, Hd, flags);

    gemm_abT<<<dim3((NV + 127) / 128, LSEQ / 128), blk, 0, stream>>>(
        Hd, Wout, bout, nullptr, out, LSEQ, NV, NH);
}

// Round 4
// 4378.189 us; speedup vs baseline: 5.4646x; 5.4638x over previous
//
#include <hip/hip_runtime.h>

#define LSEQ 512
#define NIN 1024
#define NH 2048
#define NV 50257
#define NG 8192  /* 4*NH */

typedef float f32x4 __attribute__((ext_vector_type(4)));
typedef unsigned long long u64;

// ---------------------------------------------------------------------------
// GEMM: C[M,N] = A[M,K] @ B[N,K]^T + bias1[n] (+ bias2[n] if non-null)
// BM=BN=128, BK=32, 256 threads, 8x8 microtile per thread. fp32. (unchanged)
// ---------------------------------------------------------------------------
__global__ __launch_bounds__(256, 2)
void gemm_abT(const float* __restrict__ A, const float* __restrict__ B,
              const float* __restrict__ bias1, const float* __restrict__ bias2,
              float* __restrict__ C, int M, int N, int K)
{
    __shared__ float As[32][128];   // [k][m]
    __shared__ float Bs[32][128];   // [k][n]
    const int tid = threadIdx.x;
    const int m0 = blockIdx.y * 128;
    const int n0 = blockIdx.x * 128;
    const int tx = tid & 15;        // n-dir
    const int ty = tid >> 4;        // m-dir
    const int lrow = tid >> 1;      // 0..127 row to load
    const int lk0  = (tid & 1) << 4; // 0 or 16

    float acc[8][8];
#pragma unroll
    for (int i = 0; i < 8; ++i)
#pragma unroll
        for (int j = 0; j < 8; ++j) acc[i][j] = 0.f;

    const bool bvalid = (n0 + lrow) < N;

    for (int k0 = 0; k0 < K; k0 += 32) {
        float4 va[4], vb[4];
        {
            const float* pa = A + (size_t)(m0 + lrow) * K + k0 + lk0;
#pragma unroll
            for (int q = 0; q < 4; ++q) va[q] = *(const float4*)(pa + 4 * q);
        }
#pragma unroll
        for (int q = 0; q < 4; ++q) vb[q] = make_float4(0.f, 0.f, 0.f, 0.f);
        if (bvalid) {
            const float* pb = B + (size_t)(n0 + lrow) * K + k0 + lk0;
#pragma unroll
            for (int q = 0; q < 4; ++q) vb[q] = *(const float4*)(pb + 4 * q);
        }
#pragma unroll
        for (int q = 0; q < 4; ++q) {
            As[lk0 + 4 * q + 0][lrow] = va[q].x;
            As[lk0 + 4 * q + 1][lrow] = va[q].y;
            As[lk0 + 4 * q + 2][lrow] = va[q].z;
            As[lk0 + 4 * q + 3][lrow] = va[q].w;
            Bs[lk0 + 4 * q + 0][lrow] = vb[q].x;
            Bs[lk0 + 4 * q + 1][lrow] = vb[q].y;
            Bs[lk0 + 4 * q + 2][lrow] = vb[q].z;
            Bs[lk0 + 4 * q + 3][lrow] = vb[q].w;
        }
        __syncthreads();

#pragma unroll 4
        for (int kk = 0; kk < 32; ++kk) {
            const float4 a0 = *(const float4*)&As[kk][ty * 8];
            const float4 a1 = *(const float4*)&As[kk][ty * 8 + 4];
            const float4 b0 = *(const float4*)&Bs[kk][tx * 8];
            const float4 b1 = *(const float4*)&Bs[kk][tx * 8 + 4];
            const float av[8] = {a0.x, a0.y, a0.z, a0.w, a1.x, a1.y, a1.z, a1.w};
            const float bv[8] = {b0.x, b0.y, b0.z, b0.w, b1.x, b1.y, b1.z, b1.w};
#pragma unroll
            for (int i = 0; i < 8; ++i)
#pragma unroll
                for (int j = 0; j < 8; ++j)
                    acc[i][j] = fmaf(av[i], bv[j], acc[i][j]);
        }
        __syncthreads();
    }

#pragma unroll
    for (int j = 0; j < 8; ++j) {
        const int n = n0 + tx * 8 + j;
        if (n >= N) continue;
        const float bb = bias1[n] + (bias2 ? bias2[n] : 0.f);
#pragma unroll
        for (int i = 0; i < 8; ++i) {
            const int m = m0 + ty * 8 + i;
            C[(size_t)m * N + n] = acc[i][j] + bb;
        }
    }
}

// ---------------------------------------------------------------------------
// Persistent sequential LSTM with TAGGED-VALUE RELAY (no fences, no discrete
// grid barrier). h version v (v=0..1023) lives in hbq[v&1][unit] as a 64-bit
// atom: (tag = v+1)<<32 | float_bits. Writers publish with relaxed
// agent-scope atomic stores; readers spin on relaxed agent-scope loads until
// tag matches. Tag+payload share one atom -> no release/acquire needed ->
// no buffer_wbl2/buffer_inv per step (the round-1..3 cost: ~21us/step).
// Relay dependency (each WG needs ALL tags of version v before it can
// publish v+1) bounds skew to one version -> parity double-buffer is safe.
// Stale tags from a previous replay can't alias (finals 1023/1024 vs wanted
// small; overwritten by the relay within 2 steps; plus 32KB memset each call).
// ---------------------------------------------------------------------------
__device__ __forceinline__ float sigmoidf_(float x)
{
    return 1.f / (1.f + __expf(-x));
}

__device__ __forceinline__ void tag_wait4(const u64* p0, const u64* p1,
                                          const u64* p2, const u64* p3,
                                          unsigned want, float* o)
{
    u64 a = __hip_atomic_load(p0, __ATOMIC_RELAXED, __HIP_MEMORY_SCOPE_AGENT);
    u64 b = __hip_atomic_load(p1, __ATOMIC_RELAXED, __HIP_MEMORY_SCOPE_AGENT);
    u64 c = __hip_atomic_load(p2, __ATOMIC_RELAXED, __HIP_MEMORY_SCOPE_AGENT);
    u64 d = __hip_atomic_load(p3, __ATOMIC_RELAXED, __HIP_MEMORY_SCOPE_AGENT);
    while (((unsigned)(a >> 32) != want) | ((unsigned)(b >> 32) != want) |
           ((unsigned)(c >> 32) != want) | ((unsigned)(d >> 32) != want)) {
        __builtin_amdgcn_s_sleep(1);
        a = __hip_atomic_load(p0, __ATOMIC_RELAXED, __HIP_MEMORY_SCOPE_AGENT);
        b = __hip_atomic_load(p1, __ATOMIC_RELAXED, __HIP_MEMORY_SCOPE_AGENT);
        c = __hip_atomic_load(p2, __ATOMIC_RELAXED, __HIP_MEMORY_SCOPE_AGENT);
        d = __hip_atomic_load(p3, __ATOMIC_RELAXED, __HIP_MEMORY_SCOPE_AGENT);
    }
    o[0] = __uint_as_float((unsigned)a);
    o[1] = __uint_as_float((unsigned)b);
    o[2] = __uint_as_float((unsigned)c);
    o[3] = __uint_as_float((unsigned)d);
}

#define W_LIST(F) F(0) F(1) F(2) F(3) F(4) F(5) F(6) F(7) F(8) F(9) F(10) F(11) \
  F(12) F(13) F(14) F(15) F(16) F(17) F(18) F(19) F(20) F(21) F(22) F(23) \
  F(24) F(25) F(26) F(27) F(28) F(29) F(30) F(31)
#define DECLW(I) f32x4 w##I;
#define LOADW(I) w##I = wp4[I];
#define PINW(I)  asm volatile("" : "+v"(w##I));

#define CHUNK(CH, WA, WB, WC, WD) do { \
    const f32x4 ha = *(const f32x4*)&h_s[hbase + (CH) * 16 + 0]; \
    const f32x4 hcb = *(const f32x4*)&h_s[hbase + (CH) * 16 + 4]; \
    const f32x4 hcc = *(const f32x4*)&h_s[hbase + (CH) * 16 + 8]; \
    const f32x4 hcd = *(const f32x4*)&h_s[hbase + (CH) * 16 + 12]; \
    p0 = fmaf(WA.x, ha.x, p0);  p0 = fmaf(WA.y, ha.y, p0); \
    p0 = fmaf(WA.z, ha.z, p0);  p0 = fmaf(WA.w, ha.w, p0); \
    p1 = fmaf(WB.x, hcb.x, p1); p1 = fmaf(WB.y, hcb.y, p1); \
    p1 = fmaf(WB.z, hcb.z, p1); p1 = fmaf(WB.w, hcb.w, p1); \
    p2 = fmaf(WC.x, hcc.x, p2); p2 = fmaf(WC.y, hcc.y, p2); \
    p2 = fmaf(WC.z, hcc.z, p2); p2 = fmaf(WC.w, hcc.w, p2); \
    p3 = fmaf(WD.x, hcd.x, p3); p3 = fmaf(WD.y, hcd.y, p3); \
    p3 = fmaf(WD.z, hcd.z, p3); p3 = fmaf(WD.w, hcd.w, p3); \
} while (0)

// One LSTM step. GS = global version index of the INPUT h. T = index into XP.
#define STEP(XP, T, GS, LAST, STOREHD) do { \
    float xc = 0.f; \
    if (sub == 0) xc = (XP)[(size_t)(T) * NG + grow];  /* issue before spin */ \
    { \
        const u64* hsrc = hbq + ((GS) & 1) * NH; \
        float hv[4]; \
        tag_wait4(&hsrc[tid], &hsrc[tid + 512], &hsrc[tid + 1024], &hsrc[tid + 1536], \
                  (unsigned)((GS) + 1), hv); \
        h_s[tid          + ((tid          >> 7) << 2)] = hv[0]; \
        h_s[(tid +  512) + (((tid +  512) >> 7) << 2)] = hv[1]; \
        h_s[(tid + 1024) + (((tid + 1024) >> 7) << 2)] = hv[2]; \
        h_s[(tid + 1536) + (((tid + 1536) >> 7) << 2)] = hv[3]; \
    } \
    __syncthreads(); \
    float p0 = 0.f, p1 = 0.f, p2 = 0.f, p3 = 0.f; \
    CHUNK(0, w0, w1, w2, w3);     CHUNK(1, w4, w5, w6, w7); \
    CHUNK(2, w8, w9, w10, w11);   CHUNK(3, w12, w13, w14, w15); \
    CHUNK(4, w16, w17, w18, w19); CHUNK(5, w20, w21, w22, w23); \
    CHUNK(6, w24, w25, w26, w27); CHUNK(7, w28, w29, w30, w31); \
    float partial = (p0 + p1) + (p2 + p3); \
    partial += __shfl_xor(partial, 1); \
    partial += __shfl_xor(partial, 2); \
    partial += __shfl_xor(partial, 4); \
    partial += __shfl_xor(partial, 8); \
    if (sub == 0) gates_s[row] = partial + xc; \
    __syncthreads(); \
    if (tid < 8) { \
        const float ig = sigmoidf_(gates_s[tid]); \
        const float fg = sigmoidf_(gates_s[8 + tid]); \
        const float gg = tanhf(gates_s[16 + tid]); \
        const float og = sigmoidf_(gates_s[24 + tid]); \
        const float cn = fg * c_s[tid] + ig * gg; \
        c_s[tid] = cn; \
        const float hn = og * tanhf(cn); \
        if (STOREHD) Hd[(size_t)(T) * NH + wg * 8 + tid] = hn; \
        if (!(LAST)) { \
            const u64 pv = ((u64)(unsigned)((GS) + 2) << 32) | (u64)__float_as_uint(hn); \
            __hip_atomic_store(&hbq[(((GS) + 1) & 1) * NH + wg * 8 + tid], pv, \
                               __ATOMIC_RELAXED, __HIP_MEMORY_SCOPE_AGENT); \
        } \
    } \
} while (0)

__global__ __launch_bounds__(512, 2)
void seq_lstm(const float* __restrict__ Whh_e,
              const float* __restrict__ Whh_d,
              const float* __restrict__ Xe,   // [LSEQ][NG] = Wih_e@src + biases
              const float* __restrict__ Xd,   // [LSEQ][NG]
              u64* __restrict__ hbq,          // [2][NH] tagged h relay buffers
              float* __restrict__ Hd)         // [LSEQ][NH] decoder h history
{
    const int wg   = blockIdx.x;        // 0..255
    const int tid  = threadIdx.x;       // 0..511
    const int lane = tid & 63;
    const int wv   = tid >> 6;          // 0..7
    const int row  = (wv << 2) + (lane >> 4);  // local gate-row 0..31
    const int sub  = lane & 15;                // 16 threads per row
    const int gate = row >> 3;
    const int u    = row & 7;
    const int grow = gate * NH + wg * 8 + u;   // global gate row in [0,8192)
    const int hbase = sub * 132;               // swizzled LDS base

    __shared__ float h_s[2112];   // 2048 + pad 4/128-seg (kills stride conflicts)
    __shared__ float gates_s[32];
    __shared__ float c_s[8];

    W_LIST(DECLW)

    // load encoder recurrent weights into registers (held in unified VGPR/AGPR)
    {
        const f32x4* wp4 = (const f32x4*)(Whh_e + (size_t)grow * NH + sub * 128);
        W_LIST(LOADW)
        W_LIST(PINW)
    }

    // publish h version 0 (= zeros, tag 1); the relay's first spin is the
    // implicit start barrier.
    if (tid < 8) {
        c_s[tid] = 0.f;
        const u64 v0 = ((u64)1 << 32);  // tag=1, payload=0.0f
        __hip_atomic_store(&hbq[wg * 8 + tid], v0,
                           __ATOMIC_RELAXED, __HIP_MEMORY_SCOPE_AGENT);
    }
    __syncthreads();

    // ---- encoder: input-h versions 0..511 ----
#pragma unroll 1
    for (int t = 0; t < LSEQ; ++t) {
        STEP(Xe, t, t, false, false);
    }

    // ---- switch to decoder weights (h,c carry over = "memory") ----
    {
        const f32x4* wp4 = (const f32x4*)(Whh_d + (size_t)grow * NH + sub * 128);
        W_LIST(LOADW)
        W_LIST(PINW)
    }

    // ---- decoder: input-h versions 512..1023 ----
#pragma unroll 1
    for (int t = 0; t < LSEQ; ++t) {
        STEP(Xd, t, LSEQ + t, (t == LSEQ - 1), true);
    }
}

// ---------------------------------------------------------------------------
extern "C" void kernel_launch(void* const* d_in, const int* in_sizes, int n_in,
                              void* d_out, int out_size, void* d_ws, size_t ws_size,
                              hipStream_t stream)
{
    const float* src   = (const float*)d_in[0];
    const float* tgt   = (const float*)d_in[1];
    const float* Wih_e = (const float*)d_in[2];
    const float* Whh_e = (const float*)d_in[3];
    const float* bih_e = (const float*)d_in[4];
    const float* bhh_e = (const float*)d_in[5];
    const float* Wih_d = (const float*)d_in[6];
    const float* Whh_d = (const float*)d_in[7];
    const float* bih_d = (const float*)d_in[8];
    const float* bhh_d = (const float*)d_in[9];
    const float* Wout  = (const float*)d_in[10];
    const float* bout  = (const float*)d_in[11];
    float* out = (float*)d_out;

    // workspace layout (bytes):
    //   [0, 32K)      hbq[2][2048] u64 tagged h relay (memset 0 each call)
    //   [32K, +4MB)   Hd[512][2048]
    //   [+, +16MB)    Xe[512][8192]
    //   [+, +16MB)    Xd[512][8192]
    char* ws = (char*)d_ws;
    u64*  hbq = (u64*)ws;
    float* Hd = (float*)(ws + 32768);
    float* Xe = (float*)(ws + 32768 + (size_t)LSEQ * NH * 4);
    float* Xd = Xe + (size_t)LSEQ * NG;

    hipMemsetAsync(ws, 0, 32768, stream);  // clear relay tags

    const dim3 blk(256);
    gemm_abT<<<dim3(NG / 128, LSEQ / 128), blk, 0, stream>>>(
        src, Wih_e, bih_e, bhh_e, Xe, LSEQ, NG, NIN);
    gemm_abT<<<dim3(NG / 128, LSEQ / 128), blk, 0, stream>>>(
        tgt, Wih_d, bih_d, bhh_d, Xd, LSEQ, NG, NIN);

    seq_lstm<<<dim3(256), dim3(512), 0, stream>>>(
        Whh_e, Whh_d, Xe, Xd, hbq, Hd);

    gemm_abT<<<dim3((NV + 127) / 128, LSEQ / 128), blk, 0, stream>>>(
        Hd, Wout, bout, nullptr, out, LSEQ, NV, NH);
}

// Round 5
// 3211.891 us; speedup vs baseline: 7.4488x; 1.3631x over previous
//
#include <hip/hip_runtime.h>

#define LSEQ 512
#define NIN 1024
#define NH 2048
#define NV 50257
#define NG 8192  /* 4*NH */

typedef float f32x4 __attribute__((ext_vector_type(4)));
typedef short s16x8 __attribute__((ext_vector_type(8)));
typedef unsigned long long u64;

// ---------------------------------------------------------------------------
// Split-bf16 MFMA GEMM: C[M,N] = A[M,K] @ B[N,K]^T + bias1 (+bias2).
// Each fp32 x is split x = hi + lo (bf16 RNE); A.B ~= Ah.Bh + Ah.Bl + Al.Bh
// (lo*lo term ~2^-18 relative, dropped). Error ~1e-6 relative -> fp32-class.
// BM=BN=128, BK=32, 256 thr = 4 waves (2x2), wave tile 64x64 (4x4 frags of
// 16x16), mfma_f32_16x16x32_bf16, 48 MFMA/wave/k-step. LDS rows padded to
// 40 shorts (80 B) -> frag ds_read_b128 is 2-way-conflict only (free, m136).
// M must be multiple of 128; N edge-masked; K multiple of 32.
// ---------------------------------------------------------------------------
__device__ __forceinline__ unsigned short bf16_hi_rne(float x)
{
    unsigned u = __float_as_uint(x);
    return (unsigned short)((u + 0x7fffu + ((u >> 16) & 1u)) >> 16);
}

__global__ __launch_bounds__(256, 2)
void gemm_mfma_abT(const float* __restrict__ A, const float* __restrict__ B,
                   const float* __restrict__ bias1, const float* __restrict__ bias2,
                   float* __restrict__ C, int M, int N, int K)
{
    __shared__ unsigned short Ah[128 * 40], Al[128 * 40];
    __shared__ unsigned short Bh[128 * 40], Bl[128 * 40];

    const int tid  = threadIdx.x;
    const int m0   = blockIdx.x * 128;   // x = M tiles (4): consecutive blocks share B panel
    const int n0   = blockIdx.y * 128;
    const int lrow = tid >> 1;           // 0..127
    const int lk0  = (tid & 1) << 4;     // 0 or 16
    const int lane = tid & 63;
    const int wave = tid >> 6;
    const int wm   = (wave >> 1) * 64;   // wave row offset in tile
    const int wn   = (wave & 1) * 64;    // wave col offset in tile
    const int fr   = lane & 15;          // fragment non-K index
    const int fk   = (lane >> 4) * 8;    // fragment K offset

    f32x4 acc[4][4];
#pragma unroll
    for (int i = 0; i < 4; ++i)
#pragma unroll
        for (int j = 0; j < 4; ++j) acc[i][j] = (f32x4){0.f, 0.f, 0.f, 0.f};

    const bool bvalid = (n0 + lrow) < N;
    const float* pa = A + (size_t)(m0 + lrow) * K + lk0;
    const float* pb = bvalid ? (B + (size_t)(n0 + lrow) * K + lk0) : nullptr;

    for (int k0 = 0; k0 < K; k0 += 32) {
        float4 va[4], vb[4];
#pragma unroll
        for (int q = 0; q < 4; ++q) va[q] = *(const float4*)(pa + k0 + 4 * q);
        if (bvalid) {
#pragma unroll
            for (int q = 0; q < 4; ++q) vb[q] = *(const float4*)(pb + k0 + 4 * q);
        } else {
#pragma unroll
            for (int q = 0; q < 4; ++q) vb[q] = make_float4(0.f, 0.f, 0.f, 0.f);
        }

#pragma unroll
        for (int q = 0; q < 4; ++q) {
            const float av[4] = {va[q].x, va[q].y, va[q].z, va[q].w};
            const float bv[4] = {vb[q].x, vb[q].y, vb[q].z, vb[q].w};
            ushort4 ah, alo, bh, blo;
            unsigned short* ahp = (unsigned short*)&ah;
            unsigned short* alp = (unsigned short*)&alo;
            unsigned short* bhp = (unsigned short*)&bh;
            unsigned short* blp = (unsigned short*)&blo;
#pragma unroll
            for (int j = 0; j < 4; ++j) {
                const unsigned short h = bf16_hi_rne(av[j]);
                ahp[j] = h;
                alp[j] = bf16_hi_rne(av[j] - __uint_as_float((unsigned)h << 16));
                const unsigned short g = bf16_hi_rne(bv[j]);
                bhp[j] = g;
                blp[j] = bf16_hi_rne(bv[j] - __uint_as_float((unsigned)g << 16));
            }
            const int sidx = lrow * 40 + lk0 + 4 * q;
            *(ushort4*)&Ah[sidx] = ah;
            *(ushort4*)&Al[sidx] = alo;
            *(ushort4*)&Bh[sidx] = bh;
            *(ushort4*)&Bl[sidx] = blo;
        }
        __syncthreads();

        s16x8 fah[4], fal[4], fbh[4], fbl[4];
#pragma unroll
        for (int i = 0; i < 4; ++i) {
            const int ar = (wm + i * 16 + fr) * 40 + fk;
            fah[i] = *(const s16x8*)&Ah[ar];
            fal[i] = *(const s16x8*)&Al[ar];
            const int br = (wn + i * 16 + fr) * 40 + fk;
            fbh[i] = *(const s16x8*)&Bh[br];
            fbl[i] = *(const s16x8*)&Bl[br];
        }
#pragma unroll
        for (int i = 0; i < 4; ++i)
#pragma unroll
            for (int j = 0; j < 4; ++j) {
                acc[i][j] = __builtin_amdgcn_mfma_f32_16x16x32_bf16(fah[i], fbh[j], acc[i][j], 0, 0, 0);
                acc[i][j] = __builtin_amdgcn_mfma_f32_16x16x32_bf16(fah[i], fbl[j], acc[i][j], 0, 0, 0);
                acc[i][j] = __builtin_amdgcn_mfma_f32_16x16x32_bf16(fal[i], fbh[j], acc[i][j], 0, 0, 0);
            }
        __syncthreads();
    }

    // epilogue: D row(m) = (lane>>4)*4 + r, col(n) = lane&15 (m89-verified)
    const int rbase = (lane >> 4) * 4;
#pragma unroll
    for (int j = 0; j < 4; ++j) {
        const int col = n0 + wn + j * 16 + fr;
        if (col >= N) continue;
        const float bb = bias1[col] + (bias2 ? bias2[col] : 0.f);
#pragma unroll
        for (int i = 0; i < 4; ++i) {
#pragma unroll
            for (int r = 0; r < 4; ++r) {
                const int row = m0 + wm + i * 16 + rbase + r;
                C[(size_t)row * N + col] = acc[i][j][r] + bb;
            }
        }
    }
}

// ---------------------------------------------------------------------------
// Persistent sequential LSTM with TAGGED-VALUE RELAY (unchanged from round 4:
// 2.66 ms, ~2.6 us/step). See round-4 notes: tag+payload share one 64-bit
// atom -> relaxed agent-scope atomics, zero fences in 1024 steps.
// ---------------------------------------------------------------------------
__device__ __forceinline__ float sigmoidf_(float x)
{
    return 1.f / (1.f + __expf(-x));
}

__device__ __forceinline__ void tag_wait4(const u64* p0, const u64* p1,
                                          const u64* p2, const u64* p3,
                                          unsigned want, float* o)
{
    u64 a = __hip_atomic_load(p0, __ATOMIC_RELAXED, __HIP_MEMORY_SCOPE_AGENT);
    u64 b = __hip_atomic_load(p1, __ATOMIC_RELAXED, __HIP_MEMORY_SCOPE_AGENT);
    u64 c = __hip_atomic_load(p2, __ATOMIC_RELAXED, __HIP_MEMORY_SCOPE_AGENT);
    u64 d = __hip_atomic_load(p3, __ATOMIC_RELAXED, __HIP_MEMORY_SCOPE_AGENT);
    while (((unsigned)(a >> 32) != want) | ((unsigned)(b >> 32) != want) |
           ((unsigned)(c >> 32) != want) | ((unsigned)(d >> 32) != want)) {
        __builtin_amdgcn_s_sleep(1);
        a = __hip_atomic_load(p0, __ATOMIC_RELAXED, __HIP_MEMORY_SCOPE_AGENT);
        b = __hip_atomic_load(p1, __ATOMIC_RELAXED, __HIP_MEMORY_SCOPE_AGENT);
        c = __hip_atomic_load(p2, __ATOMIC_RELAXED, __HIP_MEMORY_SCOPE_AGENT);
        d = __hip_atomic_load(p3, __ATOMIC_RELAXED, __HIP_MEMORY_SCOPE_AGENT);
    }
    o[0] = __uint_as_float((unsigned)a);
    o[1] = __uint_as_float((unsigned)b);
    o[2] = __uint_as_float((unsigned)c);
    o[3] = __uint_as_float((unsigned)d);
}

#define W_LIST(F) F(0) F(1) F(2) F(3) F(4) F(5) F(6) F(7) F(8) F(9) F(10) F(11) \
  F(12) F(13) F(14) F(15) F(16) F(17) F(18) F(19) F(20) F(21) F(22) F(23) \
  F(24) F(25) F(26) F(27) F(28) F(29) F(30) F(31)
#define DECLW(I) f32x4 w##I;
#define LOADW(I) w##I = wp4[I];
#define PINW(I)  asm volatile("" : "+v"(w##I));

#define CHUNK(CH, WA, WB, WC, WD) do { \
    const f32x4 ha = *(const f32x4*)&h_s[hbase + (CH) * 16 + 0]; \
    const f32x4 hcb = *(const f32x4*)&h_s[hbase + (CH) * 16 + 4]; \
    const f32x4 hcc = *(const f32x4*)&h_s[hbase + (CH) * 16 + 8]; \
    const f32x4 hcd = *(const f32x4*)&h_s[hbase + (CH) * 16 + 12]; \
    p0 = fmaf(WA.x, ha.x, p0);  p0 = fmaf(WA.y, ha.y, p0); \
    p0 = fmaf(WA.z, ha.z, p0);  p0 = fmaf(WA.w, ha.w, p0); \
    p1 = fmaf(WB.x, hcb.x, p1); p1 = fmaf(WB.y, hcb.y, p1); \
    p1 = fmaf(WB.z, hcb.z, p1); p1 = fmaf(WB.w, hcb.w, p1); \
    p2 = fmaf(WC.x, hcc.x, p2); p2 = fmaf(WC.y, hcc.y, p2); \
    p2 = fmaf(WC.z, hcc.z, p2); p2 = fmaf(WC.w, hcc.w, p2); \
    p3 = fmaf(WD.x, hcd.x, p3); p3 = fmaf(WD.y, hcd.y, p3); \
    p3 = fmaf(WD.z, hcd.z, p3); p3 = fmaf(WD.w, hcd.w, p3); \
} while (0)

#define STEP(XP, T, GS, LAST, STOREHD) do { \
    float xc = 0.f; \
    if (sub == 0) xc = (XP)[(size_t)(T) * NG + grow];  /* issue before spin */ \
    { \
        const u64* hsrc = hbq + ((GS) & 1) * NH; \
        float hv[4]; \
        tag_wait4(&hsrc[tid], &hsrc[tid + 512], &hsrc[tid + 1024], &hsrc[tid + 1536], \
                  (unsigned)((GS) + 1), hv); \
        h_s[tid          + ((tid          >> 7) << 2)] = hv[0]; \
        h_s[(tid +  512) + (((tid +  512) >> 7) << 2)] = hv[1]; \
        h_s[(tid + 1024) + (((tid + 1024) >> 7) << 2)] = hv[2]; \
        h_s[(tid + 1536) + (((tid + 1536) >> 7) << 2)] = hv[3]; \
    } \
    __syncthreads(); \
    float p0 = 0.f, p1 = 0.f, p2 = 0.f, p3 = 0.f; \
    CHUNK(0, w0, w1, w2, w3);     CHUNK(1, w4, w5, w6, w7); \
    CHUNK(2, w8, w9, w10, w11);   CHUNK(3, w12, w13, w14, w15); \
    CHUNK(4, w16, w17, w18, w19); CHUNK(5, w20, w21, w22, w23); \
    CHUNK(6, w24, w25, w26, w27); CHUNK(7, w28, w29, w30, w31); \
    float partial = (p0 + p1) + (p2 + p3); \
    partial += __shfl_xor(partial, 1); \
    partial += __shfl_xor(partial, 2); \
    partial += __shfl_xor(partial, 4); \
    partial += __shfl_xor(partial, 8); \
    if (sub == 0) gates_s[row] = partial + xc; \
    __syncthreads(); \
    if (tid < 8) { \
        const float ig = sigmoidf_(gates_s[tid]); \
        const float fg = sigmoidf_(gates_s[8 + tid]); \
        const float gg = tanhf(gates_s[16 + tid]); \
        const float og = sigmoidf_(gates_s[24 + tid]); \
        const float cn = fg * c_s[tid] + ig * gg; \
        c_s[tid] = cn; \
        const float hn = og * tanhf(cn); \
        if (STOREHD) Hd[(size_t)(T) * NH + wg * 8 + tid] = hn; \
        if (!(LAST)) { \
            const u64 pv = ((u64)(unsigned)((GS) + 2) << 32) | (u64)__float_as_uint(hn); \
            __hip_atomic_store(&hbq[(((GS) + 1) & 1) * NH + wg * 8 + tid], pv, \
                               __ATOMIC_RELAXED, __HIP_MEMORY_SCOPE_AGENT); \
        } \
    } \
} while (0)

__global__ __launch_bounds__(512, 2)
void seq_lstm(const float* __restrict__ Whh_e,
              const float* __restrict__ Whh_d,
              const float* __restrict__ Xe,   // [LSEQ][NG]
              const float* __restrict__ Xd,   // [LSEQ][NG]
              u64* __restrict__ hbq,          // [2][NH] tagged h relay buffers
              float* __restrict__ Hd)         // [LSEQ][NH]
{
    const int wg   = blockIdx.x;
    const int tid  = threadIdx.x;
    const int lane = tid & 63;
    const int wv   = tid >> 6;
    const int row  = (wv << 2) + (lane >> 4);
    const int sub  = lane & 15;
    const int gate = row >> 3;
    const int u    = row & 7;
    const int grow = gate * NH + wg * 8 + u;
    const int hbase = sub * 132;

    __shared__ float h_s[2112];
    __shared__ float gates_s[32];
    __shared__ float c_s[8];

    W_LIST(DECLW)

    {
        const f32x4* wp4 = (const f32x4*)(Whh_e + (size_t)grow * NH + sub * 128);
        W_LIST(LOADW)
        W_LIST(PINW)
    }

    if (tid < 8) {
        c_s[tid] = 0.f;
        const u64 v0 = ((u64)1 << 32);
        __hip_atomic_store(&hbq[wg * 8 + tid], v0,
                           __ATOMIC_RELAXED, __HIP_MEMORY_SCOPE_AGENT);
    }
    __syncthreads();

#pragma unroll 1
    for (int t = 0; t < LSEQ; ++t) {
        STEP(Xe, t, t, false, false);
    }

    {
        const f32x4* wp4 = (const f32x4*)(Whh_d + (size_t)grow * NH + sub * 128);
        W_LIST(LOADW)
        W_LIST(PINW)
    }

#pragma unroll 1
    for (int t = 0; t < LSEQ; ++t) {
        STEP(Xd, t, LSEQ + t, (t == LSEQ - 1), true);
    }
}

// ---------------------------------------------------------------------------
extern "C" void kernel_launch(void* const* d_in, const int* in_sizes, int n_in,
                              void* d_out, int out_size, void* d_ws, size_t ws_size,
                              hipStream_t stream)
{
    const float* src   = (const float*)d_in[0];
    const float* tgt   = (const float*)d_in[1];
    const float* Wih_e = (const float*)d_in[2];
    const float* Whh_e = (const float*)d_in[3];
    const float* bih_e = (const float*)d_in[4];
    const float* bhh_e = (const float*)d_in[5];
    const float* Wih_d = (const float*)d_in[6];
    const float* Whh_d = (const float*)d_in[7];
    const float* bih_d = (const float*)d_in[8];
    const float* bhh_d = (const float*)d_in[9];
    const float* Wout  = (const float*)d_in[10];
    const float* bout  = (const float*)d_in[11];
    float* out = (float*)d_out;

    // workspace layout (bytes):
    //   [0, 32K)      hbq[2][2048] u64 tagged h relay (memset 0 each call)
    //   [32K, +4MB)   Hd[512][2048]
    //   [+, +16MB)    Xe[512][8192]
    //   [+, +16MB)    Xd[512][8192]
    char* ws = (char*)d_ws;
    u64*  hbq = (u64*)ws;
    float* Hd = (float*)(ws + 32768);
    float* Xe = (float*)(ws + 32768 + (size_t)LSEQ * NH * 4);
    float* Xd = Xe + (size_t)LSEQ * NG;

    hipMemsetAsync(ws, 0, 32768, stream);

    const dim3 blk(256);
    // input-side gate GEMMs: grid.x = M tiles so same-B blocks are adjacent
    gemm_mfma_abT<<<dim3(LSEQ / 128, NG / 128), blk, 0, stream>>>(
        src, Wih_e, bih_e, bhh_e, Xe, LSEQ, NG, NIN);
    gemm_mfma_abT<<<dim3(LSEQ / 128, NG / 128), blk, 0, stream>>>(
        tgt, Wih_d, bih_d, bhh_d, Xd, LSEQ, NG, NIN);

    seq_lstm<<<dim3(256), dim3(512), 0, stream>>>(
        Whh_e, Whh_d, Xe, Xd, hbq, Hd);

    // output projection: Y = Hd @ Wout^T + bout
    gemm_mfma_abT<<<dim3(LSEQ / 128, (NV + 127) / 128), blk, 0, stream>>>(
        Hd, Wout, bout, nullptr, out, LSEQ, NV, NH);
}